// Round 15
// baseline (83.730 us; speedup 1.0000x reference)
//
#include <hip/hip_runtime.h>
#include <math.h>

// LongRangeProj forward, MI355X — R10 body + DOUBLE fwd launch (diagnostic).
// The second fwd launch overwrites d_out with identical values (idempotent);
// dur delta vs the single-launch R10 baseline (72.6 us) measures fwd's WARM
// dispatch time, discriminating: DVFS-ramp (~+8) vs slow-kernel (~+30) vs
// node-overhead (~+1) theories for the ~28 us constant seen in R6..R13.
//
// term(n,p) = A + B*fn + C0*fn^2 + C1*ang^2,  out = exp(max_n term)
//   A = ln x - rm^2*inv2rs,  B = 2*rm*inv2rs   (per node, in LDS)
//   ang^2 = d^2 + min(0, 4pi^2 - 4pi*|d|),  d = phi - theta_wrapped
// tab4[dyi][jp][wpx] (float4 = {fn,phi}x2, j=2jp,2jp+1), 491 KB, L2-resident.
// Mask point: center-pixel epilogue fmax(acc, A).

#define TWO_PI_F   6.28318530717958647692f
#define INV_2PI_F  0.15915494309189533577f
#define FOUR_PI_F  12.56637061435917295385f
#define FOUR_PI2_F 39.47841760435743447534f

__global__ __launch_bounds__(256) void lrp_geom(float4* __restrict__ tab4)
{
    const int idx = blockIdx.x * 256 + threadIdx.x;   // 0..30719
    const int wpx = idx & 63;
    const int jp  = (idx >> 6) & 3;
    const int dyi = idx >> 8;                         // 0..119
    const float dy  = (float)(dyi - 56);
    const float dxa = (float)(wpx - 16 * jp);         // j = 2*jp
    const float dxb = dxa - 8.0f;                     // j = 2*jp+1
    const float fna = sqrtf(fmaf(dxa, dxa, dy * dy));
    const float fnb = sqrtf(fmaf(dxb, dxb, dy * dy));
    const float pha = atan2f(dy, dxa);                // setup only
    const float phb = atan2f(dy, dxb);
    tab4[idx] = make_float4(fna, pha, fnb, phb);
}

__global__ __launch_bounds__(256, 8) void lrp_fwd(
    const float* __restrict__ x,
    const float* __restrict__ rmean,
    const float* __restrict__ amean,
    const float* __restrict__ rstd,
    const float* __restrict__ astd,
    const float4* __restrict__ tab4,
    float* __restrict__ out)
{
    __shared__ float4 prm[64];   // {A, B, theta_wrapped, 0} per node

    const int tid  = threadIdx.x;
    const int bc   = blockIdx.x >> 4;   // plane (b*64+c); 16 blocks per plane
    const int tile = blockIdx.x & 15;   // 256 pixels per block

    const int c = bc & 63;
    const float rs = rstd[c];
    const float as = astd[c];
    const float inv2rs = 1.0f / (2.0f * fmaf(rs, rs, 0.01f));
    const float inv2as = 1.0f / (2.0f * fmaf(as, as, 1e-4f));

    if (tid < 64) {
        const int idx = bc * 64 + tid;
        const float lx = logf(x[idx]);
        const float rm = fabsf(rmean[idx]);
        float th = amean[idx];
        th = fmaf(__builtin_rintf(th * INV_2PI_F), -TWO_PI_F, th); // [-pi,pi]
        prm[tid] = make_float4(fmaf(-(rm * rm), inv2rs, lx),
                               2.0f * rm * inv2rs, th, 0.0f);
    }

    __syncthreads();

    const int pp  = tile * 256 + tid;   // pixel in plane, 0..4095
    const int wpx = pp & 63;
    const int hpx = pp >> 6;

    const float C0 = -inv2rs;
    const float C1 = -inv2as;

    float acc = -INFINITY;

    #pragma unroll
    for (int i = 0; i < 8; ++i) {
        const float4* rowp = tab4 + ((hpx + 56 - 8 * i) * 256 + wpx);
        #pragma unroll
        for (int jp = 0; jp < 4; ++jp) {
            const float4 g  = rowp[jp * 64];          // 2 terms per dwordx4
            const float4 qa = prm[i * 8 + 2 * jp];    // wave-uniform broadcast
            const float4 qb = prm[i * 8 + 2 * jp + 1];
            {   // term a: fn=g.x, phi=g.y
                const float d   = g.y - qa.z;
                const float aa  = fmaf(d, d,
                    fminf(0.0f, fmaf(-FOUR_PI_F, fabsf(d), FOUR_PI2_F)));
                const float mid = fmaf(g.x, fmaf(g.x, C0, qa.y), qa.x);
                acc = fmaxf(acc, fmaf(aa, C1, mid));
            }
            {   // term b: fn=g.z, phi=g.w
                const float d   = g.w - qb.z;
                const float aa  = fmaf(d, d,
                    fminf(0.0f, fmaf(-FOUR_PI_F, fabsf(d), FOUR_PI2_F)));
                const float mid = fmaf(g.z, fmaf(g.z, C0, qb.y), qb.x);
                acc = fmaxf(acc, fmaf(aa, C1, mid));
            }
        }
    }

    if (((wpx & 7) | (hpx & 7)) == 0) {   // mask-point epilogue
        acc = fmaxf(acc, prm[(hpx >> 3) * 8 + (wpx >> 3)].x);
    }

    out[bc * 4096 + pp] = __expf(acc);
}

extern "C" void kernel_launch(void* const* d_in, const int* in_sizes, int n_in,
                              void* d_out, int out_size, void* d_ws, size_t ws_size,
                              hipStream_t stream) {
    const float* x     = (const float*)d_in[0];
    const float* rmean = (const float*)d_in[1];
    const float* amean = (const float*)d_in[2];
    const float* rstd  = (const float*)d_in[3];
    const float* astd  = (const float*)d_in[4];
    float* out  = (float*)d_out;
    float4* tab4 = (float4*)d_ws;       // 491.5 KB scratch; rebuilt per call

    lrp_geom<<<120, 256, 0, stream>>>(tab4);
    // Launch #1 (cold) then #2 (warm, idempotent overwrite): the dur delta vs
    // the single-launch baseline isolates fwd's warm dispatch time.
    lrp_fwd<<<2048, 256, 0, stream>>>(x, rmean, amean, rstd, astd, tab4, out);
    lrp_fwd<<<2048, 256, 0, stream>>>(x, rmean, amean, rstd, astd, tab4, out);
}